// Round 8
// baseline (3633.006 us; speedup 1.0000x reference)
//
#include <hip/hip_runtime.h>
#include <cstdint>
#include <cstddef>

typedef unsigned long long u64;

#define CIN   512
#define H     38
#define W     50
#define HW    1900
#define PH    40
#define PW    52
#define NA    17100
#define NSORT 32768
#define PRE   6000
#define POST  300
#define NW    94        // ceil(6000/64)
#define MTS   6016      // MT row stride (padded)
#define TOPN  6016      // padded top-k (>= PRE)
#define GRIDN 720
#define NTHR  256
#define NTOT  (GRIDN * NTHR)

// ANCHOR_BASE, fp32-exact decimal literals
__constant__ float c_AB[36] = {
  -37.254833f,  -82.50967f,   53.254833f,  98.50967f,
  -82.50967f,  -173.01933f,   98.50967f,  189.01933f,
 -173.01933f,  -354.03867f,  189.01933f,  370.03867f,
  -56.f, -56.f, 72.f, 72.f,
 -120.f,-120.f,136.f,136.f,
 -248.f,-248.f,264.f,264.f,
  -82.50967f,  -37.254833f,   98.50967f,  53.254833f,
 -173.01933f,  -82.50967f,   189.01933f,  98.50967f,
 -354.03867f, -173.01933f,   370.03867f, 189.01933f
};

// ---------------- software grid barrier (persistent-kernel pattern) ------------
// All 720 blocks are co-resident (LDS 16KB*3=48KB, launch_bounds caps VGPR for
// 3 blocks/CU, 720 <= 768). Arrive: agent fence + device-scope atomic inc.
// Wait: acquire-load spin (s_sleep throttled) + fence. This is what ROCm's
// grid.sync() lowers to; plain launch keeps graph capture happy (r7 lesson:
// hipLaunchCooperativeKernel is rejected under capture -> kernel never ran).
__device__ inline void gsync(unsigned* bar, unsigned target) {
  __syncthreads();
  if (threadIdx.x == 0) {
    __threadfence();
    __hip_atomic_fetch_add(bar, 1u, __ATOMIC_ACQ_REL, __HIP_MEMORY_SCOPE_AGENT);
    while (__hip_atomic_load(bar, __ATOMIC_ACQUIRE, __HIP_MEMORY_SCOPE_AGENT) < target) {
      __builtin_amdgcn_s_sleep(2);
    }
    __threadfence();
  }
  __syncthreads();
}

// ------------------------------ merge-path helper ------------------------------
__device__ inline void merge_path(const u64* __restrict__ A, int nA, const u64* __restrict__ B, int nB,
                                  u64* __restrict__ dst, int d0, int cnt, int outLimit) {
  if (d0 >= outLimit || d0 >= nA + nB) return;   // helper-local return; caller reaches barriers
  int lo = d0 > nB ? d0 - nB : 0;
  int hi = d0 < nA ? d0 : nA;
  while (lo < hi) {
    int mid = (lo + hi) >> 1;
    if (A[mid] <= B[d0 - 1 - mid]) lo = mid + 1; else hi = mid;
  }
  int i = lo, j = d0 - lo;
  int end = d0 + cnt;
  if (end > nA + nB) end = nA + nB;
  if (end > outLimit) end = outLimit;
  for (int q = d0; q < end; ++q) {
    u64 v;
    if (i < nA && (j >= nB || A[i] <= B[j])) v = A[i++]; else v = B[j++];
    dst[q] = v;
  }
}

__device__ inline u64 shfl_u64(u64 v, int src) {
  int lo = __shfl((int)(unsigned)(v & 0xffffffffull), src, 64);
  int hi = __shfl((int)(unsigned)(v >> 32), src, 64);
  return ((u64)(unsigned)hi << 32) | (unsigned)lo;
}
__device__ inline u64 shfl_u64_xor(u64 v, int m) {
  int lo = __shfl_xor((int)(unsigned)(v & 0xffffffffull), m, 64);
  int hi = __shfl_xor((int)(unsigned)(v >> 32), m, 64);
  return ((u64)(unsigned)hi << 32) | (unsigned)lo;
}

// ========== single persistent mega-kernel: all 10 phases, 9 soft barriers ======
// Round-6 ledger: ~20us/launch-boundary x 10 = ~200us of the 283us tail
// (phase compute sums to ~85us). One launch + 9 soft syncs (~5us) removes it.
// Grid 720x256 maps the conv phase 1:1 onto its counter-validated r0 config.
// All phase bodies are r6 code VERBATIM -> bit-exact output (absmax 0.0).
__global__ __launch_bounds__(256, 3) void mega_kernel(
    const float* __restrict__ x,  const float* __restrict__ w1,
    const float* __restrict__ lw, const float* __restrict__ sw,
    const float* __restrict__ b1, const float* __restrict__ lb, const float* __restrict__ sb,
    float* __restrict__ xp, float* __restrict__ wt, float* __restrict__ wt2t,
    float* __restrict__ part, float* __restrict__ h1, float* __restrict__ c2,
    float* __restrict__ roi, u64* __restrict__ keys, u64* __restrict__ m4s,
    u64* __restrict__ tmp, u64* __restrict__ mfs,
    float* __restrict__ tb, float* __restrict__ areaArr, u64* __restrict__ valw,
    u64* __restrict__ MT, float* __restrict__ out, unsigned* __restrict__ bar)
{
  __shared__ __align__(16) char smem[16384];    // aliased per phase (max: sort 16KB)
  const int tid  = threadIdx.x;
  const int bid  = blockIdx.x;
  const int gtid = bid * NTHR + tid;
  unsigned ph = 0;

  // ---------------- Phase P: pad + wt2t + wtrans (fused prep) ----------------
  for (int idx = gtid; idx < CIN * PH * PW; idx += NTOT) {
    int c   = idx / (PH * PW);
    int rem = idx - c * (PH * PW);
    int yy  = rem / PW;
    int xx  = rem - yy * PW;
    float v = 0.f;
    if (yy >= 1 && yy <= H && xx >= 1 && xx <= W)
      v = x[(size_t)c * HW + (yy - 1) * W + (xx - 1)];
    xp[idx] = v;
  }
  for (int t = gtid; t < CIN * 64; t += NTOT) {
    int k = t >> 6, o = t & 63;
    float v = 0.f;
    if (o < 36)      v = lw[o * CIN + k];
    else if (o < 54) v = sw[(o - 36) * CIN + k];
    wt2t[(size_t)o * CIN + k] = v;
  }
  {
    auto tile = reinterpret_cast<float(*)[16][17]>(smem);   // [9][16][17] = 9.6KB
    int tx = tid & 15, ty = tid >> 4;
    for (int u = bid; u < 1024; u += GRIDN) {
      int o0 = (u & 31) * 16, i0 = (u >> 5) * 16;
      __syncthreads();
      #pragma unroll
      for (int r = 0; r < 9; ++r)
        tile[r][tx][ty] = w1[((size_t)(o0 + ty) * CIN + (i0 + tx)) * 9 + r];
      __syncthreads();
      #pragma unroll
      for (int r = 0; r < 9; ++r)
        wt[((size_t)r * CIN + i0 + ty) * CIN + o0 + tx] = tile[r][ty][tx];
    }
  }
  gsync(bar, ++ph * GRIDN);

  // ---------------- Phase C: conv1 (r0 config verbatim, 720 units 1:1) --------
  {
    auto As = reinterpret_cast<float(*)[64]>(smem);
    auto Bs = reinterpret_cast<float(*)[64]>(smem + 4096);
    const int split = bid / 240;
    const int rem2  = bid - split * 240;
    const int obase = (rem2 & 7) * 64;
    const int pbase = (rem2 >> 3) * 64;
    const int kbeg = split * 1536, kend = kbeg + 1536;
    const int krow = tid >> 4;
    const int c4   = (tid & 15) * 4;
    const int to   = (tid & 15) * 4;
    const int tp   = (tid >> 4) * 4;
    float acc[4][4] = {};
    float av[4], bv[4];

    auto loadAB = [&](int k0) {
      int k = k0 + krow;
      const float* ap = &wt[(size_t)k * CIN + obase + c4];
      av[0] = ap[0]; av[1] = ap[1]; av[2] = ap[2]; av[3] = ap[3];
      int r = k >> 9;
      int i = k & 511;
      int ky = r / 3, kx = r - ky * 3;
      const float* xpi = &xp[(size_t)i * (PH * PW)];
      #pragma unroll
      for (int j = 0; j < 4; ++j) {
        int p = pbase + c4 + j;
        float v = 0.f;
        if (p < HW) {
          int y = p / W, xx2 = p - y * W;
          v = xpi[(y + ky) * PW + xx2 + kx];
        }
        bv[j] = v;
      }
    };

    loadAB(kbeg);
    for (int k0 = kbeg; k0 < kend; k0 += 16) {
      __syncthreads();
      *(float4*)&As[krow][c4] = make_float4(av[0], av[1], av[2], av[3]);
      *(float4*)&Bs[krow][c4] = make_float4(bv[0], bv[1], bv[2], bv[3]);
      __syncthreads();
      if (k0 + 16 < kend) loadAB(k0 + 16);
      #pragma unroll
      for (int kk = 0; kk < 16; ++kk) {
        float4 a4 = *(const float4*)&As[kk][to];
        float4 b4 = *(const float4*)&Bs[kk][tp];
        float ar[4] = {a4.x, a4.y, a4.z, a4.w};
        float br[4] = {b4.x, b4.y, b4.z, b4.w};
        #pragma unroll
        for (int ii = 0; ii < 4; ++ii)
          #pragma unroll
          for (int jj = 0; jj < 4; ++jj)
            acc[ii][jj] += ar[ii] * br[jj];
      }
    }
    float* dst = part + (size_t)split * CIN * HW;
    #pragma unroll
    for (int ii = 0; ii < 4; ++ii) {
      int o = obase + to + ii;
      int p = pbase + tp;
      float* rowp = dst + (size_t)o * HW;
      if (p + 3 < HW) {
        *(float4*)&rowp[p] = make_float4(acc[ii][0], acc[ii][1], acc[ii][2], acc[ii][3]);
      } else {
        #pragma unroll
        for (int jj = 0; jj < 4; ++jj) if (p + jj < HW) rowp[p + jj] = acc[ii][jj];
      }
    }
  }
  gsync(bar, ++ph * GRIDN);

  // ---------------- Phase R: h1 = relu(part0+part1+part2 + bias) --------------
  for (int idx = gtid; idx < CIN * HW; idx += NTOT) {
    int o = idx / HW;
    float v = part[idx] + part[(size_t)CIN * HW + idx] + part[(size_t)2 * CIN * HW + idx] + b1[o];
    h1[idx] = v > 0.f ? v : 0.f;
  }
  gsync(bar, ++ph * GRIDN);

  // ---------------- Phase H: heads per-wave dot products ----------------------
  {
    int wid = gtid >> 6;                         // wave units 0..1619
    if (wid < 54 * 30) {
      const int o  = wid / 30;
      const int pg = wid - o * 30;
      const int p  = pg * 64 + (tid & 63);
      const bool pv = (p < HW);
      const float* __restrict__ ap = wt2t + ((size_t)o << 9);
      const float* __restrict__ bp = h1 + (pv ? p : 0);
      float acc = 0.f;
      #pragma unroll 1
      for (int g = 0; g < CIN; g += 16) {
        float4 a0 = *(const float4*)(ap + g);
        float4 a1 = *(const float4*)(ap + g + 4);
        float4 a2 = *(const float4*)(ap + g + 8);
        float4 a3 = *(const float4*)(ap + g + 12);
        float bb[16];
        #pragma unroll
        for (int u = 0; u < 16; ++u) bb[u] = bp[(size_t)(g + u) * HW];
        acc += a0.x * bb[0];  acc += a0.y * bb[1];  acc += a0.z * bb[2];  acc += a0.w * bb[3];
        acc += a1.x * bb[4];  acc += a1.y * bb[5];  acc += a1.z * bb[6];  acc += a1.w * bb[7];
        acc += a2.x * bb[8];  acc += a2.y * bb[9];  acc += a2.z * bb[10]; acc += a2.w * bb[11];
        acc += a3.x * bb[12]; acc += a3.y * bb[13]; acc += a3.z * bb[14]; acc += a3.w * bb[15];
      }
      if (pv) {
        float bias = (o < 36) ? lb[o] : sb[o - 36];
        c2[(size_t)o * HW + p] = acc + bias;
      }
    }
  }
  gsync(bar, ++ph * GRIDN);

  // ---------------- Phase D: decode anchors -> roi, keys ----------------------
  if (gtid < NSORT) {
    int n = gtid;
    if (n >= NA) {
      keys[n] = ~0ull;
    } else {
      unsigned p = (unsigned)n / 9u;
      unsigned a = (unsigned)n - p * 9u;
      unsigned y = p / 50u;
      unsigned xu = p - y * 50u;
      float dy = c2[(a * 4 + 0) * HW + p];
      float dx = c2[(a * 4 + 1) * HW + p];
      float dh = c2[(a * 4 + 2) * HW + p];
      float dw = c2[(a * 4 + 3) * HW + p];
      float fg = c2[(37 + a * 2) * HW + p];
      float sy = (float)(y * 16u), sx = (float)(xu * 16u);
      float ay1 = sy + c_AB[a * 4 + 0], ax1 = sx + c_AB[a * 4 + 1];
      float ay2 = sy + c_AB[a * 4 + 2], ax2 = sx + c_AB[a * 4 + 3];
      float ahh = ay2 - ay1, aww = ax2 - ax1;
      float acy = ay1 + 0.5f * ahh, acx = ax1 + 0.5f * aww;
      float cy = dy * ahh + acy, cx = dx * aww + acx;
      float hh = expf(dh) * ahh, ww = expf(dw) * aww;
      float y1 = cy - 0.5f * hh, x1 = cx - 0.5f * ww;
      float y2 = cy + 0.5f * hh, x2 = cx + 0.5f * ww;
      y1 = fminf(fmaxf(y1, 0.f), 608.f); x1 = fminf(fmaxf(x1, 0.f), 800.f);
      y2 = fminf(fmaxf(y2, 0.f), 608.f); x2 = fminf(fmaxf(x2, 0.f), 800.f);
      *(float4*)&roi[(size_t)n * 4] = make_float4(y1, x1, y2, x2);
      bool valid = ((y2 - y1) >= 16.f) && ((x2 - x1) >= 16.f);
      float sc = valid ? fg : -__builtin_huge_valf();
      unsigned m = __float_as_uint(sc);
      m = (m & 0x80000000u) ? ~m : (m | 0x80000000u);
      unsigned km = ~m;
      keys[n] = ((u64)km << 32) | (unsigned)n;
    }
  }
  gsync(bar, ++ph * GRIDN);

  // ---------------- Phase S: 16 blocks LDS-bitonic-sort 2048 each -------------
  if (bid < 16) {
    u64* s = (u64*)smem;                         // 16KB
    u64* base = keys + (size_t)bid * 2048;
    for (int i = tid; i < 2048; i += 256) s[i] = base[i];
    __syncthreads();
    for (int k = 2; k <= 2048; k <<= 1) {
      for (int j = k >> 1; j > 0; j >>= 1) {
        for (int i = tid; i < 2048; i += 256) {
          int l = i ^ j;
          if (l > i) {
            u64 xa = s[i], xb = s[l];
            bool up = ((i & k) == 0);
            if ((xa > xb) == up) { s[i] = xb; s[l] = xa; }
          }
        }
        __syncthreads();
      }
    }
    for (int i = tid; i < 2048; i += 256) base[i] = s[i];
  }
  gsync(bar, ++ph * GRIDN);

  // ---------------- Phase M4: 4 blocks, 4-way merge -> tmp (global scratch) ---
  if (bid < 4) {
    u64* M01 = m4s + (size_t)bid * 8192;
    u64* M23 = M01 + 4096;
    const u64* c = keys + (size_t)bid * 8192;
    merge_path(c,        2048, c + 2048, 2048, M01, tid * 16, 16, 4096);
    merge_path(c + 4096, 2048, c + 6144, 2048, M23, tid * 16, 16, 4096);
    __threadfence();
    __syncthreads();
    merge_path(M01, 4096, M23, 4096, tmp + (size_t)bid * TOPN, tid * 24, 24, TOPN);
  }
  gsync(bar, ++ph * GRIDN);

  // ------- Phase MF: block 0 final merges (global scratch) + fused gather -----
  if (bid == 0) {
    u64* L0 = mfs;
    u64* L1 = mfs + TOPN;
    u64* F  = mfs + 2 * TOPN;
    merge_path(tmp,            TOPN, tmp + TOPN,     TOPN, L0, tid * 24, 24, TOPN);
    merge_path(tmp + 2 * TOPN, TOPN, tmp + 3 * TOPN, TOPN, L1, tid * 24, 24, TOPN);
    __threadfence();
    __syncthreads();
    merge_path(L0, TOPN, L1, TOPN, F, tid * 24, 24, TOPN);
    __threadfence();
    __syncthreads();
    for (int j0 = 0; j0 < TOPN; j0 += 256) {
      int j = j0 + tid;
      u64 key = F[j];
      bool valid = (j < PRE) && ((unsigned)(key >> 32) < 0xFF800000u);
      if (j < PRE) {
        unsigned idx = (unsigned)key;
        float4 bx = *(const float4*)&roi[(size_t)idx * 4];
        *(float4*)&tb[(size_t)j * 4] = bx;
        areaArr[j] = (bx.z - bx.x) * (bx.w - bx.y);
      }
      u64 mask = __ballot(valid);
      if ((tid & 63) == 0) {
        int wi = j >> 6;
        if (wi < NW) valw[wi] = mask;
      }
    }
  }
  gsync(bar, ++ph * GRIDN);

  // ---------------- Phase MK: suppression bit-matrix (grid-stride) ------------
  for (int linear = gtid; linear < NW * PRE; linear += NTOT) {
    int w = linear / PRE;
    int i = linear - w * PRE;
    u64 bits = 0;
    int jbase = w * 64;
    if (jbase + 63 > i) {
      float4 bi = *(const float4*)&tb[(size_t)i * 4];
      float ai = areaArr[i];
      int jend = jbase + 64; if (jend > PRE) jend = PRE;
      int jst = jbase > i + 1 ? jbase : i + 1;
      for (int j = jst; j < jend; ++j) {
        float4 bj = *(const float4*)&tb[(size_t)j * 4];
        float ty1 = fmaxf(bi.x, bj.x);
        float tx1 = fmaxf(bi.y, bj.y);
        float ty2 = fminf(bi.z, bj.z);
        float tx2 = fminf(bi.w, bj.w);
        float ih = ty2 - ty1; if (ih < 0.f) ih = 0.f;
        float iw = tx2 - tx1; if (iw < 0.f) iw = 0.f;
        float inter = ih * iw;
        float denom = ai + areaArr[j] - inter;
        if (denom < 1e-9f) denom = 1e-9f;
        if (inter / denom > 0.7f) bits |= (1ull << (j - jbase));
      }
    }
    MT[(size_t)w * MTS + i] = bits;
  }
  gsync(bar, ++ph * GRIDN);

  // ---------------- Phase N: greedy NMS (block 0, wave 0 only) ----------------
  if (bid == 0 && tid < 64) {
    int* keepids = (int*)smem;
    const int lane = tid;
    int kept = 0;
    bool done = false;
    for (int g = 0; g < NW && !done; ++g) {
      const u64* __restrict__ rowg = MT + (size_t)g * MTS;
      u64 rem = 0;
      for (int base = 0; base < kept; base += 64) {
        int kidx = base + lane;
        u64 v = (kidx < kept) ? rowg[keepids[kidx]] : 0ull;
        rem |= v;
      }
      #pragma unroll
      for (int s2 = 32; s2 > 0; s2 >>= 1) rem |= shfl_u64_xor(rem, s2);
      int row = g * 64 + lane;
      u64 cur = (row < PRE) ? rowg[row] : 0ull;
      u64 remaining = valw[g] & ~rem;
      while (remaining) {                        // uniform across lanes
        int c = __builtin_ctzll(remaining);
        if (lane == 0) keepids[kept] = g * 64 + c;
        ++kept;
        if (kept >= POST) { done = true; break; }
        u64 cw = shfl_u64(cur, c);
        u64 above = (c == 63) ? 0ull : (~0ull << (c + 1));
        remaining = remaining & ~cw & above;
      }
    }
    int kmax = kept < POST ? kept : POST;
    for (int rr = lane; rr < kmax; rr += 64) {
      float4 bx = *(const float4*)&tb[(size_t)keepids[rr] * 4];
      *(float4*)&out[(size_t)rr * 4] = bx;
    }
  }
}

extern "C" void kernel_launch(void* const* d_in, const int* in_sizes, int n_in,
                              void* d_out, int out_size, void* d_ws, size_t ws_size,
                              hipStream_t stream) {
  (void)in_sizes; (void)n_in; (void)ws_size;
  const float* x  = (const float*)d_in[0];
  const float* w1 = (const float*)d_in[1];
  const float* b1 = (const float*)d_in[2];
  const float* lw = (const float*)d_in[3];
  const float* lb = (const float*)d_in[4];
  const float* sw = (const float*)d_in[5];
  const float* sb = (const float*)d_in[6];
  float* out = (float*)d_out;

  char* wp = (char*)d_ws;
  auto alloc = [&](size_t b) -> void* { void* p = wp; wp += (b + 255) & ~(size_t)255; return p; };
  float* xp      = (float*)alloc((size_t)CIN * PH * PW * 4);   // 4.26 MB
  float* wt      = (float*)alloc((size_t)4608 * CIN * 4);      // 9.44 MB
  float* part    = (float*)alloc((size_t)3 * CIN * HW * 4);    // 11.7 MB
  float* h1      = (float*)alloc((size_t)CIN * HW * 4);        // 3.89 MB
  float* wt2t    = (float*)alloc((size_t)64 * CIN * 4);
  float* c2      = (float*)alloc((size_t)64 * HW * 4);
  float* roi     = (float*)alloc((size_t)NA * 4 * 4);
  u64*   keys    = (u64*)alloc((size_t)NSORT * 8);
  u64*   m4s     = (u64*)alloc((size_t)4 * 8192 * 8);          // merge4 scratch
  u64*   tmp     = (u64*)alloc((size_t)4 * TOPN * 8);
  u64*   mfs     = (u64*)alloc((size_t)3 * TOPN * 8);          // final-merge scratch
  float* tb      = (float*)alloc((size_t)PRE * 4 * 4);
  float* areaArr = (float*)alloc((size_t)PRE * 4);
  u64*   valw    = (u64*)alloc((size_t)NW * 8);
  u64*   MT      = (u64*)alloc((size_t)NW * MTS * 8);          // 4.52 MB
  unsigned* bar  = (unsigned*)alloc(256);                      // barrier counter

  hipMemsetAsync(d_out, 0, (size_t)out_size * 4, stream);
  hipMemsetAsync(bar, 0, 256, stream);                         // reset each replay

  mega_kernel<<<GRIDN, NTHR, 0, stream>>>(
      x, w1, lw, sw, b1, lb, sb,
      xp, wt, wt2t, part, h1, c2,
      roi, keys, m4s, tmp, mfs,
      tb, areaArr, valw, MT, out, bar);
}

// Round 9
// 605.336 us; speedup vs baseline: 6.0016x; 6.0016x over previous
//
#include <hip/hip_runtime.h>
#include <cstdint>
#include <cstddef>

typedef unsigned long long u64;

#define CIN   512
#define H     38
#define W     50
#define HW    1900
#define PH    40
#define PW    52
#define NA    17100
#define NSORT 32768
#define PRE   6000
#define POST  300
#define NW    94        // ceil(6000/64)
#define MTS   6016      // MT row stride (padded)
#define TOPN  6016      // padded top-k (>= PRE)

// ANCHOR_BASE, fp32-exact decimal literals
__constant__ float c_AB[36] = {
  -37.254833f,  -82.50967f,   53.254833f,  98.50967f,
  -82.50967f,  -173.01933f,   98.50967f,  189.01933f,
 -173.01933f,  -354.03867f,  189.01933f,  370.03867f,
  -56.f, -56.f, 72.f, 72.f,
 -120.f,-120.f,136.f,136.f,
 -248.f,-248.f,264.f,264.f,
  -82.50967f,  -37.254833f,   98.50967f,  53.254833f,
 -173.01933f,  -82.50967f,   189.01933f,  98.50967f,
 -354.03867f, -173.01933f,   370.03867f, 189.01933f
};

// ----------------- fused prep: pad (4160 blks) + wtrans (1024 blks) ------------
__global__ __launch_bounds__(256) void prep_kernel(const float* __restrict__ x, float* __restrict__ xp,
                                                   const float* __restrict__ w1, float* __restrict__ wt) {
  __shared__ float tile[9][16][17];
  int b = blockIdx.x;
  if (b < 4160) {                                    // ---- pad ----
    int idx = b * 256 + threadIdx.x;                 // exactly 512*40*52
    int c   = idx / (PH * PW);
    int rem = idx - c * (PH * PW);
    int yy  = rem / PW;
    int xx  = rem - yy * PW;
    float v = 0.f;
    if (yy >= 1 && yy <= H && xx >= 1 && xx <= W)
      v = x[(size_t)c * HW + (yy - 1) * W + (xx - 1)];
    xp[idx] = v;
  } else {                                           // ---- wtrans ----
    int t2 = b - 4160;
    int o0 = (t2 & 31) * 16, i0 = (t2 >> 5) * 16;
    int tx = threadIdx.x & 15, ty = threadIdx.x >> 4;
    #pragma unroll
    for (int r = 0; r < 9; ++r)
      tile[r][tx][ty] = w1[((size_t)(o0 + ty) * CIN + (i0 + tx)) * 9 + r];
    __syncthreads();
    #pragma unroll
    for (int r = 0; r < 9; ++r)
      wt[((size_t)r * CIN + i0 + ty) * CIN + o0 + tx] = tile[r][ty][tx];
  }
}

// --------- conv1 as implicit GEMM, fp32, deterministic 3-way K-split ----------
// r0 configuration VERBATIM: 64x64 tile, 4x4 micro, 720 blocks (2.8 waves/SIMD).
// Counter-validated LDS-pipe wall (171us model == measured). Bit-exact k-order.
__global__ __launch_bounds__(256) void conv_gemm_kernel(const float* __restrict__ wt, const float* __restrict__ xp,
                                                        float* __restrict__ part) {
  __shared__ __align__(16) float As[16][64];
  __shared__ __align__(16) float Bs[16][64];
  const int tid   = threadIdx.x;
  const int obase = blockIdx.x * 64;
  const int pbase = blockIdx.y * 64;
  const int split = blockIdx.z;
  const int kbeg = split * 1536, kend = kbeg + 1536;
  const int krow = tid >> 4;          // staging row 0..15
  const int c4   = (tid & 15) * 4;    // staging col
  const int to   = (tid & 15) * 4;    // output o quad
  const int tp   = (tid >> 4) * 4;    // output p quad
  float acc[4][4] = {};
  float av[4], bv[4];

  auto loadAB = [&](int k0) {
    int k = k0 + krow;
    const float* ap = &wt[(size_t)k * CIN + obase + c4];
    av[0] = ap[0]; av[1] = ap[1]; av[2] = ap[2]; av[3] = ap[3];
    int r = k >> 9;            // k = r*512 + i
    int i = k & 511;
    int ky = r / 3, kx = r - ky * 3;
    const float* xpi = &xp[(size_t)i * (PH * PW)];
    #pragma unroll
    for (int j = 0; j < 4; ++j) {
      int p = pbase + c4 + j;
      float v = 0.f;
      if (p < HW) {
        int y = p / W, xx = p - y * W;
        v = xpi[(y + ky) * PW + xx + kx];
      }
      bv[j] = v;
    }
  };

  loadAB(kbeg);
  for (int k0 = kbeg; k0 < kend; k0 += 16) {
    __syncthreads();
    *(float4*)&As[krow][c4] = make_float4(av[0], av[1], av[2], av[3]);
    *(float4*)&Bs[krow][c4] = make_float4(bv[0], bv[1], bv[2], bv[3]);
    __syncthreads();
    if (k0 + 16 < kend) loadAB(k0 + 16);
    #pragma unroll
    for (int kk = 0; kk < 16; ++kk) {
      float4 a4 = *(const float4*)&As[kk][to];
      float4 b4 = *(const float4*)&Bs[kk][tp];
      float ar[4] = {a4.x, a4.y, a4.z, a4.w};
      float br[4] = {b4.x, b4.y, b4.z, b4.w};
      #pragma unroll
      for (int ii = 0; ii < 4; ++ii)
        #pragma unroll
        for (int jj = 0; jj < 4; ++jj)
          acc[ii][jj] += ar[ii] * br[jj];
    }
  }
  float* dst = part + (size_t)split * CIN * HW;
  #pragma unroll
  for (int ii = 0; ii < 4; ++ii) {
    int o = obase + to + ii;
    int p = pbase + tp;
    float* rowp = dst + (size_t)o * HW;
    if (p + 3 < HW) {
      *(float4*)&rowp[p] = make_float4(acc[ii][0], acc[ii][1], acc[ii][2], acc[ii][3]);
    } else {
      #pragma unroll
      for (int jj = 0; jj < 4; ++jj) if (p + jj < HW) rowp[p + jj] = acc[ii][jj];
    }
  }
}

// ------------------- h1 = relu(part0+part1+part2 + bias) ----------------------
__global__ __launch_bounds__(256) void reduce_relu_kernel(const float* __restrict__ part, const float* __restrict__ b1,
                                                          float* __restrict__ h1) {
  int idx = blockIdx.x * 256 + threadIdx.x;          // exactly 512*1900
  int o = idx / HW;
  float v = part[idx] + part[(size_t)CIN * HW + idx] + part[(size_t)2 * CIN * HW + idx] + b1[o];
  h1[idx] = v > 0.f ? v : 0.f;
}

// ----------- heads as per-wave dot products, reading lw/sw DIRECTLY -----------
// wt2t[o][k] was exactly lw/sw rows concatenated -> read the source, drop the
// prep copy. Bit-exact: identical values, identical ascending-k fma order.
__global__ __launch_bounds__(64) void heads_dot_kernel(const float* __restrict__ lw, const float* __restrict__ sw,
                                                       const float* __restrict__ lb, const float* __restrict__ sb,
                                                       const float* __restrict__ h1, float* __restrict__ c2) {
  const int o = blockIdx.x;                          // 0..53
  const int p = blockIdx.y * 64 + threadIdx.x;
  const bool pv = (p < HW);
  const float* __restrict__ ap = (o < 36) ? (lw + (size_t)o * CIN) : (sw + (size_t)(o - 36) * CIN);
  const float* __restrict__ bp = h1 + (pv ? p : 0);
  float acc = 0.f;
  #pragma unroll 1
  for (int g = 0; g < CIN; g += 16) {
    float4 a0 = *(const float4*)(ap + g);
    float4 a1 = *(const float4*)(ap + g + 4);
    float4 a2 = *(const float4*)(ap + g + 8);
    float4 a3 = *(const float4*)(ap + g + 12);
    float bb[16];
    #pragma unroll
    for (int u = 0; u < 16; ++u) bb[u] = bp[(size_t)(g + u) * HW];
    acc += a0.x * bb[0];  acc += a0.y * bb[1];  acc += a0.z * bb[2];  acc += a0.w * bb[3];
    acc += a1.x * bb[4];  acc += a1.y * bb[5];  acc += a1.z * bb[6];  acc += a1.w * bb[7];
    acc += a2.x * bb[8];  acc += a2.y * bb[9];  acc += a2.z * bb[10]; acc += a2.w * bb[11];
    acc += a3.x * bb[12]; acc += a3.y * bb[13]; acc += a3.z * bb[14]; acc += a3.w * bb[15];
  }
  if (pv) {
    float bias = (o < 36) ? lb[o] : sb[o - 36];
    c2[(size_t)o * HW + p] = acc + bias;
  }
}

// ------- fused decode + LDS bitonic sort: 16 blocks, 2048 keys each ------------
// Each block decodes its own n-range straight into LDS (writes roi on the way),
// sorts, writes keys. Removes the decode launch + a 32768-key global round-trip.
__global__ __launch_bounds__(256) void decode_sort_kernel(const float* __restrict__ c2, float* __restrict__ roi,
                                                          u64* __restrict__ keys) {
  __shared__ u64 s[2048];
  const int tid = threadIdx.x;
  const int nbase = blockIdx.x * 2048;
  for (int i = tid; i < 2048; i += 256) {
    int n = nbase + i;
    u64 key;
    if (n >= NA) {
      key = ~0ull;
    } else {
      unsigned p = (unsigned)n / 9u;
      unsigned a = (unsigned)n - p * 9u;
      unsigned y = p / 50u;
      unsigned xu = p - y * 50u;
      float dy = c2[(a * 4 + 0) * HW + p];
      float dx = c2[(a * 4 + 1) * HW + p];
      float dh = c2[(a * 4 + 2) * HW + p];
      float dw = c2[(a * 4 + 3) * HW + p];
      float fg = c2[(37 + a * 2) * HW + p];         // score channel a*2+1, rows offset 36
      float sy = (float)(y * 16u), sx = (float)(xu * 16u);
      float ay1 = sy + c_AB[a * 4 + 0], ax1 = sx + c_AB[a * 4 + 1];
      float ay2 = sy + c_AB[a * 4 + 2], ax2 = sx + c_AB[a * 4 + 3];
      float ahh = ay2 - ay1, aww = ax2 - ax1;
      float acy = ay1 + 0.5f * ahh, acx = ax1 + 0.5f * aww;
      float cy = dy * ahh + acy, cx = dx * aww + acx;
      float hh = expf(dh) * ahh, ww = expf(dw) * aww;
      float y1 = cy - 0.5f * hh, x1 = cx - 0.5f * ww;
      float y2 = cy + 0.5f * hh, x2 = cx + 0.5f * ww;
      y1 = fminf(fmaxf(y1, 0.f), 608.f); x1 = fminf(fmaxf(x1, 0.f), 800.f);
      y2 = fminf(fmaxf(y2, 0.f), 608.f); x2 = fminf(fmaxf(x2, 0.f), 800.f);
      *(float4*)&roi[(size_t)n * 4] = make_float4(y1, x1, y2, x2);
      bool valid = ((y2 - y1) >= 16.f) && ((x2 - x1) >= 16.f);
      float sc = valid ? fg : -__builtin_huge_valf();
      unsigned m = __float_as_uint(sc);
      m = (m & 0x80000000u) ? ~m : (m | 0x80000000u);  // monotone map
      unsigned km = ~m;                                 // ascending = descending score
      key = ((u64)km << 32) | (unsigned)n;
    }
    s[i] = key;
  }
  __syncthreads();
  for (int k = 2; k <= 2048; k <<= 1) {
    for (int j = k >> 1; j > 0; j >>= 1) {
      for (int i = tid; i < 2048; i += 256) {
        int l = i ^ j;
        if (l > i) {
          u64 xa = s[i], xb = s[l];
          bool up = ((i & k) == 0);
          if ((xa > xb) == up) { s[i] = xb; s[l] = xa; }
        }
      }
      __syncthreads();
    }
  }
  for (int i = tid; i < 2048; i += 256) keys[nbase + i] = s[i];
}

// ------------------------------ merge-path helper ------------------------------
__device__ inline void merge_path(const u64* __restrict__ A, int nA, const u64* __restrict__ B, int nB,
                                  u64* __restrict__ dst, int d0, int cnt, int outLimit) {
  if (d0 >= outLimit || d0 >= nA + nB) return;
  int lo = d0 > nB ? d0 - nB : 0;
  int hi = d0 < nA ? d0 : nA;
  while (lo < hi) {
    int mid = (lo + hi) >> 1;
    if (A[mid] <= B[d0 - 1 - mid]) lo = mid + 1; else hi = mid;
  }
  int i = lo, j = d0 - lo;
  int end = d0 + cnt;
  if (end > nA + nB) end = nA + nB;
  if (end > outLimit) end = outLimit;
  for (int q = d0; q < end; ++q) {
    u64 v;
    if (i < nA && (j >= nB || A[i] <= B[j])) v = A[i++]; else v = B[j++];
    dst[q] = v;
  }
}

// ---- single-block 16->1 merge tree (4 levels, global scratch) + fused gather ---
// Unique keys -> any merge tree produces the identical top-6016 sequence (r4).
// Same-block global write->syncthreads->read is coherent (one CU's L1/L2).
__global__ __launch_bounds__(256) void mergeall_gather_kernel(const u64* __restrict__ keys,
                                                              u64* __restrict__ g1, u64* __restrict__ g2,
                                                              u64* __restrict__ g3,
                                                              const float* __restrict__ roi,
                                                              float* __restrict__ tb, float* __restrict__ areaArr,
                                                              u64* __restrict__ valw) {
  __shared__ u64 F[TOPN];                            // 48KB
  const int tid = threadIdx.x;
  // L1: 8 merges of 2048+2048 -> g1[m*4096]
  {
    int m = tid >> 5, d = (tid & 31) * 128;
    const u64* c = keys + (size_t)m * 4096;
    merge_path(c, 2048, c + 2048, 2048, g1 + (size_t)m * 4096, d, 128, 4096);
  }
  __threadfence(); __syncthreads();
  // L2: 4 merges of 4096+4096 -> g2[m*TOPN], capped 6016
  {
    int m = tid >> 6, d = (tid & 63) * 94;
    const u64* c = g1 + (size_t)m * 8192;
    merge_path(c, 4096, c + 4096, 4096, g2 + (size_t)m * TOPN, d, 94, TOPN);
  }
  __threadfence(); __syncthreads();
  // L3: 2 merges of 6016+6016 -> g3[m*TOPN], capped 6016
  {
    int m = tid >> 7, d = (tid & 127) * 47;
    const u64* c = g2 + (size_t)(2 * m) * TOPN;
    merge_path(c, TOPN, c + TOPN, TOPN, g3 + (size_t)m * TOPN, d, 47, TOPN);
  }
  __threadfence(); __syncthreads();
  // L4: final merge -> F (LDS), capped 6016
  merge_path(g3, TOPN, g3 + TOPN, TOPN, F, tid * 24, 24, TOPN);
  __syncthreads();
  // fused gather (verbatim r6 math)
  for (int j0 = 0; j0 < TOPN; j0 += 256) {
    int j = j0 + tid;
    u64 key = F[j];
    bool valid = (j < PRE) && ((unsigned)(key >> 32) < 0xFF800000u);   // score > -inf
    if (j < PRE) {
      unsigned idx = (unsigned)key;
      float4 bx = *(const float4*)&roi[(size_t)idx * 4];
      *(float4*)&tb[(size_t)j * 4] = bx;
      areaArr[j] = (bx.z - bx.x) * (bx.w - bx.y);
    }
    u64 mask = __ballot(valid);
    if ((tid & 63) == 0) {
      int wi = j >> 6;
      if (wi < NW) valw[wi] = mask;
    }
  }
}

// --------------- suppression bit-matrix MT[w][i]: bits j in word w -------------
__global__ __launch_bounds__(256) void mask_kernel(const float* __restrict__ tb, const float* __restrict__ areaArr,
                                                   u64* __restrict__ MT) {
  int linear = blockIdx.x * 256 + threadIdx.x;
  if (linear >= NW * PRE) return;
  int w = linear / PRE;
  int i = linear - w * PRE;
  u64 bits = 0;
  int jbase = w * 64;
  if (jbase + 63 > i) {
    float4 bi = *(const float4*)&tb[(size_t)i * 4];
    float ai = areaArr[i];
    int jend = jbase + 64; if (jend > PRE) jend = PRE;
    int jst = jbase > i + 1 ? jbase : i + 1;
    for (int j = jst; j < jend; ++j) {
      float4 bj = *(const float4*)&tb[(size_t)j * 4];
      float ty1 = fmaxf(bi.x, bj.x);
      float tx1 = fmaxf(bi.y, bj.y);
      float ty2 = fminf(bi.z, bj.z);
      float tx2 = fminf(bi.w, bj.w);
      float ih = ty2 - ty1; if (ih < 0.f) ih = 0.f;
      float iw = tx2 - tx1; if (iw < 0.f) iw = 0.f;
      float inter = ih * iw;
      float denom = ai + areaArr[j] - inter;
      if (denom < 1e-9f) denom = 1e-9f;
      if (inter / denom > 0.7f) bits |= (1ull << (j - jbase));
    }
  }
  MT[(size_t)w * MTS + i] = bits;
}

__device__ inline u64 shfl_u64(u64 v, int src) {
  int lo = __shfl((int)(unsigned)(v & 0xffffffffull), src, 64);
  int hi = __shfl((int)(unsigned)(v >> 32), src, 64);
  return ((u64)(unsigned)hi << 32) | (unsigned)lo;
}
__device__ inline u64 shfl_u64_xor(u64 v, int m) {
  int lo = __shfl_xor((int)(unsigned)(v & 0xffffffffull), m, 64);
  int hi = __shfl_xor((int)(unsigned)(v >> 32), m, 64);
  return ((u64)(unsigned)hi << 32) | (unsigned)lo;
}

// --------- single-wave greedy NMS, demand-pull rem (verbatim r6) ---------------
__global__ __launch_bounds__(64) void nms_scan_kernel(const u64* __restrict__ MT, const u64* __restrict__ valw,
                                                      const float* __restrict__ tb, float* __restrict__ out) {
  __shared__ int keepids[POST];
  const int lane = threadIdx.x;
  int kept = 0;
  bool done = false;
  for (int g = 0; g < NW && !done; ++g) {
    const u64* __restrict__ rowg = MT + (size_t)g * MTS;
    u64 rem = 0;
    for (int base = 0; base < kept; base += 64) {
      int kidx = base + lane;
      u64 v = (kidx < kept) ? rowg[keepids[kidx]] : 0ull;
      rem |= v;
    }
    #pragma unroll
    for (int s = 32; s > 0; s >>= 1) rem |= shfl_u64_xor(rem, s);
    int row = g * 64 + lane;
    u64 cur = (row < PRE) ? rowg[row] : 0ull;        // own-word suppression bits
    u64 remaining = valw[g] & ~rem;
    while (remaining) {                               // uniform across lanes
      int c = __builtin_ctzll(remaining);
      if (lane == 0) keepids[kept] = g * 64 + c;
      ++kept;
      if (kept >= POST) { done = true; break; }
      u64 cw = shfl_u64(cur, c);                      // broadcast lane c's word
      u64 above = (c == 63) ? 0ull : (~0ull << (c + 1));
      remaining = remaining & ~cw & above;
    }
  }
  __syncthreads();
  int kmax = kept < POST ? kept : POST;
  for (int rr = lane; rr < kmax; rr += 64) {
    float4 b = *(const float4*)&tb[(size_t)keepids[rr] * 4];
    *(float4*)&out[(size_t)rr * 4] = b;
  }
}

extern "C" void kernel_launch(void* const* d_in, const int* in_sizes, int n_in,
                              void* d_out, int out_size, void* d_ws, size_t ws_size,
                              hipStream_t stream) {
  (void)in_sizes; (void)n_in; (void)ws_size;
  const float* x  = (const float*)d_in[0];
  const float* w1 = (const float*)d_in[1];
  const float* b1 = (const float*)d_in[2];
  const float* lw = (const float*)d_in[3];
  const float* lb = (const float*)d_in[4];
  const float* sw = (const float*)d_in[5];
  const float* sb = (const float*)d_in[6];
  float* out = (float*)d_out;

  char* wp = (char*)d_ws;
  auto alloc = [&](size_t b) -> void* { void* p = wp; wp += (b + 255) & ~(size_t)255; return p; };
  float* xp      = (float*)alloc((size_t)CIN * PH * PW * 4);   // 4.26 MB
  float* wt      = (float*)alloc((size_t)4608 * CIN * 4);      // 9.44 MB
  float* part    = (float*)alloc((size_t)3 * CIN * HW * 4);    // 11.7 MB
  float* h1      = (float*)alloc((size_t)CIN * HW * 4);        // 3.89 MB
  float* c2      = (float*)alloc((size_t)64 * HW * 4);
  float* roi     = (float*)alloc((size_t)NA * 4 * 4);
  u64*   keys    = (u64*)alloc((size_t)NSORT * 8);
  u64*   g1      = (u64*)alloc((size_t)NSORT * 8);             // merge L1 scratch
  u64*   g2      = (u64*)alloc((size_t)4 * TOPN * 8);          // merge L2 scratch
  u64*   g3      = (u64*)alloc((size_t)2 * TOPN * 8);          // merge L3 scratch
  float* tb      = (float*)alloc((size_t)PRE * 4 * 4);
  float* areaArr = (float*)alloc((size_t)PRE * 4);
  u64*   valw    = (u64*)alloc((size_t)NW * 8);
  u64*   MT      = (u64*)alloc((size_t)NW * MTS * 8);          // 4.52 MB

  hipMemsetAsync(d_out, 0, (size_t)out_size * 4, stream);

  prep_kernel<<<5184, 256, 0, stream>>>(x, xp, w1, wt);
  conv_gemm_kernel<<<dim3(8, 30, 3), 256, 0, stream>>>(wt, xp, part);
  reduce_relu_kernel<<<(CIN * HW) / 256, 256, 0, stream>>>(part, b1, h1);
  heads_dot_kernel<<<dim3(54, 30), 64, 0, stream>>>(lw, sw, lb, sb, h1, c2);
  decode_sort_kernel<<<16, 256, 0, stream>>>(c2, roi, keys);
  mergeall_gather_kernel<<<1, 256, 0, stream>>>(keys, g1, g2, g3, roi, tb, areaArr, valw);
  mask_kernel<<<(NW * PRE + 255) / 256, 256, 0, stream>>>(tb, areaArr, MT);
  nms_scan_kernel<<<1, 64, 0, stream>>>(MT, valw, tb, out);
}

// Round 10
// 462.993 us; speedup vs baseline: 7.8468x; 1.3074x over previous
//
#include <hip/hip_runtime.h>
#include <cstdint>
#include <cstddef>

typedef unsigned long long u64;

#define CIN   512
#define H     38
#define W     50
#define HW    1900
#define PH    40
#define PW    52
#define NA    17100
#define NSORT 32768
#define PRE   6000
#define POST  300
#define NW    94        // ceil(6000/64)
#define MTS   6016      // MT row stride (padded)
#define TOPN  6016      // padded top-k (>= PRE)

// ANCHOR_BASE, fp32-exact decimal literals
__constant__ float c_AB[36] = {
  -37.254833f,  -82.50967f,   53.254833f,  98.50967f,
  -82.50967f,  -173.01933f,   98.50967f,  189.01933f,
 -173.01933f,  -354.03867f,  189.01933f,  370.03867f,
  -56.f, -56.f, 72.f, 72.f,
 -120.f,-120.f,136.f,136.f,
 -248.f,-248.f,264.f,264.f,
  -82.50967f,  -37.254833f,   98.50967f,  53.254833f,
 -173.01933f,  -82.50967f,   189.01933f,  98.50967f,
 -354.03867f, -173.01933f,   370.03867f, 189.01933f
};

// ----------------- fused prep: pad (4160 blks) + wtrans (1024 blks) ------------
__global__ __launch_bounds__(256) void prep_kernel(const float* __restrict__ x, float* __restrict__ xp,
                                                   const float* __restrict__ w1, float* __restrict__ wt) {
  __shared__ float tile[9][16][17];
  int b = blockIdx.x;
  if (b < 4160) {                                    // ---- pad ----
    int idx = b * 256 + threadIdx.x;                 // exactly 512*40*52
    int c   = idx / (PH * PW);
    int rem = idx - c * (PH * PW);
    int yy  = rem / PW;
    int xx  = rem - yy * PW;
    float v = 0.f;
    if (yy >= 1 && yy <= H && xx >= 1 && xx <= W)
      v = x[(size_t)c * HW + (yy - 1) * W + (xx - 1)];
    xp[idx] = v;
  } else {                                           // ---- wtrans ----
    int t2 = b - 4160;
    int o0 = (t2 & 31) * 16, i0 = (t2 >> 5) * 16;
    int tx = threadIdx.x & 15, ty = threadIdx.x >> 4;
    #pragma unroll
    for (int r = 0; r < 9; ++r)
      tile[r][tx][ty] = w1[((size_t)(o0 + ty) * CIN + (i0 + tx)) * 9 + r];
    __syncthreads();
    #pragma unroll
    for (int r = 0; r < 9; ++r)
      wt[((size_t)r * CIN + i0 + ty) * CIN + o0 + tx] = tile[r][ty][tx];
  }
}

// --------- conv1 as implicit GEMM, fp32, deterministic 3-way K-split ----------
// r0 configuration VERBATIM: 64x64 tile, 4x4 micro, 720 blocks (2.8 waves/SIMD).
// Counter-validated LDS-pipe wall (171us model == measured). Bit-exact k-order.
__global__ __launch_bounds__(256) void conv_gemm_kernel(const float* __restrict__ wt, const float* __restrict__ xp,
                                                        float* __restrict__ part) {
  __shared__ __align__(16) float As[16][64];
  __shared__ __align__(16) float Bs[16][64];
  const int tid   = threadIdx.x;
  const int obase = blockIdx.x * 64;
  const int pbase = blockIdx.y * 64;
  const int split = blockIdx.z;
  const int kbeg = split * 1536, kend = kbeg + 1536;
  const int krow = tid >> 4;          // staging row 0..15
  const int c4   = (tid & 15) * 4;    // staging col
  const int to   = (tid & 15) * 4;    // output o quad
  const int tp   = (tid >> 4) * 4;    // output p quad
  float acc[4][4] = {};
  float av[4], bv[4];

  auto loadAB = [&](int k0) {
    int k = k0 + krow;
    const float* ap = &wt[(size_t)k * CIN + obase + c4];
    av[0] = ap[0]; av[1] = ap[1]; av[2] = ap[2]; av[3] = ap[3];
    int r = k >> 9;            // k = r*512 + i
    int i = k & 511;
    int ky = r / 3, kx = r - ky * 3;
    const float* xpi = &xp[(size_t)i * (PH * PW)];
    #pragma unroll
    for (int j = 0; j < 4; ++j) {
      int p = pbase + c4 + j;
      float v = 0.f;
      if (p < HW) {
        int y = p / W, xx = p - y * W;
        v = xpi[(y + ky) * PW + xx + kx];
      }
      bv[j] = v;
    }
  };

  loadAB(kbeg);
  for (int k0 = kbeg; k0 < kend; k0 += 16) {
    __syncthreads();
    *(float4*)&As[krow][c4] = make_float4(av[0], av[1], av[2], av[3]);
    *(float4*)&Bs[krow][c4] = make_float4(bv[0], bv[1], bv[2], bv[3]);
    __syncthreads();
    if (k0 + 16 < kend) loadAB(k0 + 16);
    #pragma unroll
    for (int kk = 0; kk < 16; ++kk) {
      float4 a4 = *(const float4*)&As[kk][to];
      float4 b4 = *(const float4*)&Bs[kk][tp];
      float ar[4] = {a4.x, a4.y, a4.z, a4.w};
      float br[4] = {b4.x, b4.y, b4.z, b4.w};
      #pragma unroll
      for (int ii = 0; ii < 4; ++ii)
        #pragma unroll
        for (int jj = 0; jj < 4; ++jj)
          acc[ii][jj] += ar[ii] * br[jj];
    }
  }
  float* dst = part + (size_t)split * CIN * HW;
  #pragma unroll
  for (int ii = 0; ii < 4; ++ii) {
    int o = obase + to + ii;
    int p = pbase + tp;
    float* rowp = dst + (size_t)o * HW;
    if (p + 3 < HW) {
      *(float4*)&rowp[p] = make_float4(acc[ii][0], acc[ii][1], acc[ii][2], acc[ii][3]);
    } else {
      #pragma unroll
      for (int jj = 0; jj < 4; ++jj) if (p + jj < HW) rowp[p + jj] = acc[ii][jj];
    }
  }
}

// ------------------- h1 = relu(part0+part1+part2 + bias) ----------------------
__global__ __launch_bounds__(256) void reduce_relu_kernel(const float* __restrict__ part, const float* __restrict__ b1,
                                                          float* __restrict__ h1) {
  int idx = blockIdx.x * 256 + threadIdx.x;          // exactly 512*1900
  int o = idx / HW;
  float v = part[idx] + part[(size_t)CIN * HW + idx] + part[(size_t)2 * CIN * HW + idx] + b1[o];
  h1[idx] = v > 0.f ? v : 0.f;
}

// ----------- heads as per-wave dot products, reading lw/sw DIRECTLY -----------
__global__ __launch_bounds__(64) void heads_dot_kernel(const float* __restrict__ lw, const float* __restrict__ sw,
                                                       const float* __restrict__ lb, const float* __restrict__ sb,
                                                       const float* __restrict__ h1, float* __restrict__ c2) {
  const int o = blockIdx.x;                          // 0..53
  const int p = blockIdx.y * 64 + threadIdx.x;
  const bool pv = (p < HW);
  const float* __restrict__ ap = (o < 36) ? (lw + (size_t)o * CIN) : (sw + (size_t)(o - 36) * CIN);
  const float* __restrict__ bp = h1 + (pv ? p : 0);
  float acc = 0.f;
  #pragma unroll 1
  for (int g = 0; g < CIN; g += 16) {
    float4 a0 = *(const float4*)(ap + g);
    float4 a1 = *(const float4*)(ap + g + 4);
    float4 a2 = *(const float4*)(ap + g + 8);
    float4 a3 = *(const float4*)(ap + g + 12);
    float bb[16];
    #pragma unroll
    for (int u = 0; u < 16; ++u) bb[u] = bp[(size_t)(g + u) * HW];
    acc += a0.x * bb[0];  acc += a0.y * bb[1];  acc += a0.z * bb[2];  acc += a0.w * bb[3];
    acc += a1.x * bb[4];  acc += a1.y * bb[5];  acc += a1.z * bb[6];  acc += a1.w * bb[7];
    acc += a2.x * bb[8];  acc += a2.y * bb[9];  acc += a2.z * bb[10]; acc += a2.w * bb[11];
    acc += a3.x * bb[12]; acc += a3.y * bb[13]; acc += a3.z * bb[14]; acc += a3.w * bb[15];
  }
  if (pv) {
    float bias = (o < 36) ? lb[o] : sb[o - 36];
    c2[(size_t)o * HW + p] = acc + bias;
  }
}

// ------- fused decode + LDS bitonic sort: 16 blocks, 2048 keys each ------------
__global__ __launch_bounds__(256) void decode_sort_kernel(const float* __restrict__ c2, float* __restrict__ roi,
                                                          u64* __restrict__ keys) {
  __shared__ u64 s[2048];
  const int tid = threadIdx.x;
  const int nbase = blockIdx.x * 2048;
  for (int i = tid; i < 2048; i += 256) {
    int n = nbase + i;
    u64 key;
    if (n >= NA) {
      key = ~0ull;
    } else {
      unsigned p = (unsigned)n / 9u;
      unsigned a = (unsigned)n - p * 9u;
      unsigned y = p / 50u;
      unsigned xu = p - y * 50u;
      float dy = c2[(a * 4 + 0) * HW + p];
      float dx = c2[(a * 4 + 1) * HW + p];
      float dh = c2[(a * 4 + 2) * HW + p];
      float dw = c2[(a * 4 + 3) * HW + p];
      float fg = c2[(37 + a * 2) * HW + p];         // score channel a*2+1, rows offset 36
      float sy = (float)(y * 16u), sx = (float)(xu * 16u);
      float ay1 = sy + c_AB[a * 4 + 0], ax1 = sx + c_AB[a * 4 + 1];
      float ay2 = sy + c_AB[a * 4 + 2], ax2 = sx + c_AB[a * 4 + 3];
      float ahh = ay2 - ay1, aww = ax2 - ax1;
      float acy = ay1 + 0.5f * ahh, acx = ax1 + 0.5f * aww;
      float cy = dy * ahh + acy, cx = dx * aww + acx;
      float hh = expf(dh) * ahh, ww = expf(dw) * aww;
      float y1 = cy - 0.5f * hh, x1 = cx - 0.5f * ww;
      float y2 = cy + 0.5f * hh, x2 = cx + 0.5f * ww;
      y1 = fminf(fmaxf(y1, 0.f), 608.f); x1 = fminf(fmaxf(x1, 0.f), 800.f);
      y2 = fminf(fmaxf(y2, 0.f), 608.f); x2 = fminf(fmaxf(x2, 0.f), 800.f);
      *(float4*)&roi[(size_t)n * 4] = make_float4(y1, x1, y2, x2);
      bool valid = ((y2 - y1) >= 16.f) && ((x2 - x1) >= 16.f);
      float sc = valid ? fg : -__builtin_huge_valf();
      unsigned m = __float_as_uint(sc);
      m = (m & 0x80000000u) ? ~m : (m | 0x80000000u);  // monotone map
      unsigned km = ~m;                                 // ascending = descending score
      key = ((u64)km << 32) | (unsigned)n;
    }
    s[i] = key;
  }
  __syncthreads();
  for (int k = 2; k <= 2048; k <<= 1) {
    for (int j = k >> 1; j > 0; j >>= 1) {
      for (int i = tid; i < 2048; i += 256) {
        int l = i ^ j;
        if (l > i) {
          u64 xa = s[i], xb = s[l];
          bool up = ((i & k) == 0);
          if ((xa > xb) == up) { s[i] = xb; s[l] = xa; }
        }
      }
      __syncthreads();
    }
  }
  for (int i = tid; i < 2048; i += 256) keys[nbase + i] = s[i];
}

// ------------------------------ merge-path helper ------------------------------
__device__ inline void merge_path(const u64* __restrict__ A, int nA, const u64* __restrict__ B, int nB,
                                  u64* __restrict__ dst, int d0, int cnt, int outLimit) {
  if (d0 >= outLimit || d0 >= nA + nB) return;
  int lo = d0 > nB ? d0 - nB : 0;
  int hi = d0 < nA ? d0 : nA;
  while (lo < hi) {
    int mid = (lo + hi) >> 1;
    if (A[mid] <= B[d0 - 1 - mid]) lo = mid + 1; else hi = mid;
  }
  int i = lo, j = d0 - lo;
  int end = d0 + cnt;
  if (end > nA + nB) end = nA + nB;
  if (end > outLimit) end = outLimit;
  for (int q = d0; q < end; ++q) {
    u64 v;
    if (i < nA && (j >= nB || A[i] <= B[j])) v = A[i++]; else v = B[j++];
    dst[q] = v;
  }
}

// ------- 4-way merge (2 levels in LDS), truncated to first 6016, 4 blocks ------
// r6-verbatim (r9 lesson: single-block 128-el serial merge runs = 202us latency
// chain; keep runs at 16-24 el with LDS intermediates).
__global__ __launch_bounds__(256) void merge4_kernel(const u64* __restrict__ keys, u64* __restrict__ tmp) {
  __shared__ u64 M01[4096];
  __shared__ u64 M23[4096];
  const int tid = threadIdx.x;
  const u64* c = keys + (size_t)blockIdx.x * 8192;
  merge_path(c,        2048, c + 2048, 2048, M01, tid * 16, 16, 4096);
  merge_path(c + 4096, 2048, c + 6144, 2048, M23, tid * 16, 16, 4096);
  __syncthreads();
  merge_path(M01, 4096, M23, 4096, tmp + (size_t)blockIdx.x * TOPN, tid * 24, 24, TOPN);
}

// --- final: 4 lists of 6016 -> top-6016 (LDS) + fused gather (r6-verbatim) -----
__global__ __launch_bounds__(256) void mergefinal_gather_kernel(const u64* __restrict__ tmp,
                                                                const float* __restrict__ roi,
                                                                float* __restrict__ tb, float* __restrict__ areaArr,
                                                                u64* __restrict__ valw) {
  __shared__ u64 L0[TOPN];
  __shared__ u64 L1[TOPN];
  __shared__ u64 F[TOPN];
  const int tid = threadIdx.x;
  merge_path(tmp,            TOPN, tmp + TOPN,     TOPN, L0, tid * 24, 24, TOPN);
  merge_path(tmp + 2 * TOPN, TOPN, tmp + 3 * TOPN, TOPN, L1, tid * 24, 24, TOPN);
  __syncthreads();
  merge_path(L0, TOPN, L1, TOPN, F, tid * 24, 24, TOPN);
  __syncthreads();
  for (int j0 = 0; j0 < TOPN; j0 += 256) {
    int j = j0 + tid;
    u64 key = F[j];
    bool valid = (j < PRE) && ((unsigned)(key >> 32) < 0xFF800000u);   // score > -inf
    if (j < PRE) {
      unsigned idx = (unsigned)key;
      float4 bx = *(const float4*)&roi[(size_t)idx * 4];
      *(float4*)&tb[(size_t)j * 4] = bx;
      areaArr[j] = (bx.z - bx.x) * (bx.w - bx.y);
    }
    u64 mask = __ballot(valid);
    if ((tid & 63) == 0) {
      int wi = j >> 6;
      if (wi < NW) valw[wi] = mask;
    }
  }
}

// --------------- suppression bit-matrix MT[w][i]: bits j in word w -------------
__global__ __launch_bounds__(256) void mask_kernel(const float* __restrict__ tb, const float* __restrict__ areaArr,
                                                   u64* __restrict__ MT) {
  int linear = blockIdx.x * 256 + threadIdx.x;
  if (linear >= NW * PRE) return;
  int w = linear / PRE;
  int i = linear - w * PRE;
  u64 bits = 0;
  int jbase = w * 64;
  if (jbase + 63 > i) {
    float4 bi = *(const float4*)&tb[(size_t)i * 4];
    float ai = areaArr[i];
    int jend = jbase + 64; if (jend > PRE) jend = PRE;
    int jst = jbase > i + 1 ? jbase : i + 1;
    for (int j = jst; j < jend; ++j) {
      float4 bj = *(const float4*)&tb[(size_t)j * 4];
      float ty1 = fmaxf(bi.x, bj.x);
      float tx1 = fmaxf(bi.y, bj.y);
      float ty2 = fminf(bi.z, bj.z);
      float tx2 = fminf(bi.w, bj.w);
      float ih = ty2 - ty1; if (ih < 0.f) ih = 0.f;
      float iw = tx2 - tx1; if (iw < 0.f) iw = 0.f;
      float inter = ih * iw;
      float denom = ai + areaArr[j] - inter;
      if (denom < 1e-9f) denom = 1e-9f;
      if (inter / denom > 0.7f) bits |= (1ull << (j - jbase));
    }
  }
  MT[(size_t)w * MTS + i] = bits;
}

__device__ inline u64 shfl_u64(u64 v, int src) {
  int lo = __shfl((int)(unsigned)(v & 0xffffffffull), src, 64);
  int hi = __shfl((int)(unsigned)(v >> 32), src, 64);
  return ((u64)(unsigned)hi << 32) | (unsigned)lo;
}
__device__ inline u64 shfl_u64_xor(u64 v, int m) {
  int lo = __shfl_xor((int)(unsigned)(v & 0xffffffffull), m, 64);
  int hi = __shfl_xor((int)(unsigned)(v >> 32), m, 64);
  return ((u64)(unsigned)hi << 32) | (unsigned)lo;
}

// --------- single-wave greedy NMS, demand-pull rem (verbatim r6) ---------------
__global__ __launch_bounds__(64) void nms_scan_kernel(const u64* __restrict__ MT, const u64* __restrict__ valw,
                                                      const float* __restrict__ tb, float* __restrict__ out) {
  __shared__ int keepids[POST];
  const int lane = threadIdx.x;
  int kept = 0;
  bool done = false;
  for (int g = 0; g < NW && !done; ++g) {
    const u64* __restrict__ rowg = MT + (size_t)g * MTS;
    u64 rem = 0;
    for (int base = 0; base < kept; base += 64) {
      int kidx = base + lane;
      u64 v = (kidx < kept) ? rowg[keepids[kidx]] : 0ull;
      rem |= v;
    }
    #pragma unroll
    for (int s = 32; s > 0; s >>= 1) rem |= shfl_u64_xor(rem, s);
    int row = g * 64 + lane;
    u64 cur = (row < PRE) ? rowg[row] : 0ull;        // own-word suppression bits
    u64 remaining = valw[g] & ~rem;
    while (remaining) {                               // uniform across lanes
      int c = __builtin_ctzll(remaining);
      if (lane == 0) keepids[kept] = g * 64 + c;
      ++kept;
      if (kept >= POST) { done = true; break; }
      u64 cw = shfl_u64(cur, c);                      // broadcast lane c's word
      u64 above = (c == 63) ? 0ull : (~0ull << (c + 1));
      remaining = remaining & ~cw & above;
    }
  }
  __syncthreads();
  int kmax = kept < POST ? kept : POST;
  for (int rr = lane; rr < kmax; rr += 64) {
    float4 b = *(const float4*)&tb[(size_t)keepids[rr] * 4];
    *(float4*)&out[(size_t)rr * 4] = b;
  }
}

extern "C" void kernel_launch(void* const* d_in, const int* in_sizes, int n_in,
                              void* d_out, int out_size, void* d_ws, size_t ws_size,
                              hipStream_t stream) {
  (void)in_sizes; (void)n_in; (void)ws_size;
  const float* x  = (const float*)d_in[0];
  const float* w1 = (const float*)d_in[1];
  const float* b1 = (const float*)d_in[2];
  const float* lw = (const float*)d_in[3];
  const float* lb = (const float*)d_in[4];
  const float* sw = (const float*)d_in[5];
  const float* sb = (const float*)d_in[6];
  float* out = (float*)d_out;

  char* wp = (char*)d_ws;
  auto alloc = [&](size_t b) -> void* { void* p = wp; wp += (b + 255) & ~(size_t)255; return p; };
  float* xp      = (float*)alloc((size_t)CIN * PH * PW * 4);   // 4.26 MB
  float* wt      = (float*)alloc((size_t)4608 * CIN * 4);      // 9.44 MB
  float* part    = (float*)alloc((size_t)3 * CIN * HW * 4);    // 11.7 MB
  float* h1      = (float*)alloc((size_t)CIN * HW * 4);        // 3.89 MB
  float* c2      = (float*)alloc((size_t)64 * HW * 4);
  float* roi     = (float*)alloc((size_t)NA * 4 * 4);
  u64*   keys    = (u64*)alloc((size_t)NSORT * 8);
  u64*   tmp     = (u64*)alloc((size_t)4 * TOPN * 8);
  float* tb      = (float*)alloc((size_t)PRE * 4 * 4);
  float* areaArr = (float*)alloc((size_t)PRE * 4);
  u64*   valw    = (u64*)alloc((size_t)NW * 8);
  u64*   MT      = (u64*)alloc((size_t)NW * MTS * 8);          // 4.52 MB

  hipMemsetAsync(d_out, 0, (size_t)out_size * 4, stream);

  prep_kernel<<<5184, 256, 0, stream>>>(x, xp, w1, wt);
  conv_gemm_kernel<<<dim3(8, 30, 3), 256, 0, stream>>>(wt, xp, part);
  reduce_relu_kernel<<<(CIN * HW) / 256, 256, 0, stream>>>(part, b1, h1);
  heads_dot_kernel<<<dim3(54, 30), 64, 0, stream>>>(lw, sw, lb, sb, h1, c2);
  decode_sort_kernel<<<16, 256, 0, stream>>>(c2, roi, keys);
  merge4_kernel<<<4, 256, 0, stream>>>(keys, tmp);
  mergefinal_gather_kernel<<<1, 256, 0, stream>>>(tmp, roi, tb, areaArr, valw);
  mask_kernel<<<(NW * PRE + 255) / 256, 256, 0, stream>>>(tb, areaArr, MT);
  nms_scan_kernel<<<1, 64, 0, stream>>>(MT, valw, tb, out);
}

// Round 11
// 460.662 us; speedup vs baseline: 7.8865x; 1.0051x over previous
//
#include <hip/hip_runtime.h>
#include <cstdint>
#include <cstddef>

typedef unsigned long long u64;

#define CIN   512
#define H     38
#define W     50
#define HW    1900
#define PH    40
#define PW    52
#define NA    17100
#define NSORT 32768
#define PRE   6000
#define POST  300
#define NW    94        // ceil(6000/64)
#define MTS   6016      // MT row stride (padded)
#define TOPN  6016      // padded top-k (>= PRE)
#define PB    8         // p-chunk for relu_heads (238 blocks ~ 1/CU)

// ANCHOR_BASE, fp32-exact decimal literals
__constant__ float c_AB[36] = {
  -37.254833f,  -82.50967f,   53.254833f,  98.50967f,
  -82.50967f,  -173.01933f,   98.50967f,  189.01933f,
 -173.01933f,  -354.03867f,  189.01933f,  370.03867f,
  -56.f, -56.f, 72.f, 72.f,
 -120.f,-120.f,136.f,136.f,
 -248.f,-248.f,264.f,264.f,
  -82.50967f,  -37.254833f,   98.50967f,  53.254833f,
 -173.01933f,  -82.50967f,   189.01933f,  98.50967f,
 -354.03867f, -173.01933f,   370.03867f, 189.01933f
};

// ----------------- fused prep: pad (4160 blks) + wtrans (1024 blks) ------------
__global__ __launch_bounds__(256) void prep_kernel(const float* __restrict__ x, float* __restrict__ xp,
                                                   const float* __restrict__ w1, float* __restrict__ wt) {
  __shared__ float tile[9][16][17];
  int b = blockIdx.x;
  if (b < 4160) {                                    // ---- pad ----
    int idx = b * 256 + threadIdx.x;                 // exactly 512*40*52
    int c   = idx / (PH * PW);
    int rem = idx - c * (PH * PW);
    int yy  = rem / PW;
    int xx  = rem - yy * PW;
    float v = 0.f;
    if (yy >= 1 && yy <= H && xx >= 1 && xx <= W)
      v = x[(size_t)c * HW + (yy - 1) * W + (xx - 1)];
    xp[idx] = v;
  } else {                                           // ---- wtrans ----
    int t2 = b - 4160;
    int o0 = (t2 & 31) * 16, i0 = (t2 >> 5) * 16;
    int tx = threadIdx.x & 15, ty = threadIdx.x >> 4;
    #pragma unroll
    for (int r = 0; r < 9; ++r)
      tile[r][tx][ty] = w1[((size_t)(o0 + ty) * CIN + (i0 + tx)) * 9 + r];
    __syncthreads();
    #pragma unroll
    for (int r = 0; r < 9; ++r)
      wt[((size_t)r * CIN + i0 + ty) * CIN + o0 + tx] = tile[r][ty][tx];
  }
}

// --------- conv1 as implicit GEMM, fp32, deterministic 3-way K-split ----------
// r0 configuration VERBATIM: 64x64 tile, 4x4 micro, 720 blocks (2.8 waves/SIMD).
// Counter-validated LDS-pipe wall (171us model == measured). Bit-exact k-order.
__global__ __launch_bounds__(256) void conv_gemm_kernel(const float* __restrict__ wt, const float* __restrict__ xp,
                                                        float* __restrict__ part) {
  __shared__ __align__(16) float As[16][64];
  __shared__ __align__(16) float Bs[16][64];
  const int tid   = threadIdx.x;
  const int obase = blockIdx.x * 64;
  const int pbase = blockIdx.y * 64;
  const int split = blockIdx.z;
  const int kbeg = split * 1536, kend = kbeg + 1536;
  const int krow = tid >> 4;          // staging row 0..15
  const int c4   = (tid & 15) * 4;    // staging col
  const int to   = (tid & 15) * 4;    // output o quad
  const int tp   = (tid >> 4) * 4;    // output p quad
  float acc[4][4] = {};
  float av[4], bv[4];

  auto loadAB = [&](int k0) {
    int k = k0 + krow;
    const float* ap = &wt[(size_t)k * CIN + obase + c4];
    av[0] = ap[0]; av[1] = ap[1]; av[2] = ap[2]; av[3] = ap[3];
    int r = k >> 9;            // k = r*512 + i
    int i = k & 511;
    int ky = r / 3, kx = r - ky * 3;
    const float* xpi = &xp[(size_t)i * (PH * PW)];
    #pragma unroll
    for (int j = 0; j < 4; ++j) {
      int p = pbase + c4 + j;
      float v = 0.f;
      if (p < HW) {
        int y = p / W, xx = p - y * W;
        v = xpi[(y + ky) * PW + xx + kx];
      }
      bv[j] = v;
    }
  };

  loadAB(kbeg);
  for (int k0 = kbeg; k0 < kend; k0 += 16) {
    __syncthreads();
    *(float4*)&As[krow][c4] = make_float4(av[0], av[1], av[2], av[3]);
    *(float4*)&Bs[krow][c4] = make_float4(bv[0], bv[1], bv[2], bv[3]);
    __syncthreads();
    if (k0 + 16 < kend) loadAB(k0 + 16);
    #pragma unroll
    for (int kk = 0; kk < 16; ++kk) {
      float4 a4 = *(const float4*)&As[kk][to];
      float4 b4 = *(const float4*)&Bs[kk][tp];
      float ar[4] = {a4.x, a4.y, a4.z, a4.w};
      float br[4] = {b4.x, b4.y, b4.z, b4.w};
      #pragma unroll
      for (int ii = 0; ii < 4; ++ii)
        #pragma unroll
        for (int jj = 0; jj < 4; ++jj)
          acc[ii][jj] += ar[ii] * br[jj];
    }
  }
  float* dst = part + (size_t)split * CIN * HW;
  #pragma unroll
  for (int ii = 0; ii < 4; ++ii) {
    int o = obase + to + ii;
    int p = pbase + tp;
    float* rowp = dst + (size_t)o * HW;
    if (p + 3 < HW) {
      *(float4*)&rowp[p] = make_float4(acc[ii][0], acc[ii][1], acc[ii][2], acc[ii][3]);
    } else {
      #pragma unroll
      for (int jj = 0; jj < 4; ++jj) if (p + jj < HW) rowp[p + jj] = acc[ii][jj];
    }
  }
}

// ---- fused relu+heads: h1 column slab in LDS, c2 out; h1 never materialized ---
// 238 blocks (p-chunk 8) keeps ~256 CUs covered (r9 lesson: fusions must not
// concentrate work). Phase 1: h1c[o][pp] = relu(part0+part1+part2+b1) -- same
// value & fp order as old reduce_relu. Phase 2: c2[o2][p] = dot(lw/sw row,
// h1c[:,pp]) with the IDENTICAL 16-step ascending-k sequence as heads_dot.
// LDS b-reads are 8-distinct-word broadcasts (conflict-free).
__global__ __launch_bounds__(256) void relu_heads_kernel(const float* __restrict__ part, const float* __restrict__ b1,
                                                         const float* __restrict__ lw, const float* __restrict__ sw,
                                                         const float* __restrict__ lb, const float* __restrict__ sb,
                                                         float* __restrict__ c2) {
  __shared__ float h1c[CIN][PB];                     // 16KB
  const int tid = threadIdx.x;
  const int p0  = blockIdx.x * PB;
  // phase 1: relu slab
  for (int e = tid; e < CIN * PB; e += 256) {
    int o  = e >> 3;
    int pp = e & (PB - 1);
    int p  = p0 + pp;
    float v = 0.f;
    if (p < HW) {
      size_t idx = (size_t)o * HW + p;
      v = part[idx] + part[(size_t)CIN * HW + idx] + part[(size_t)2 * CIN * HW + idx] + b1[o];
      v = v > 0.f ? v : 0.f;
    }
    h1c[o][pp] = v;
  }
  __syncthreads();
  // phase 2: heads dots from LDS
  for (int u = tid; u < 54 * PB; u += 256) {
    int o  = u >> 3;
    int pp = u & (PB - 1);
    int p  = p0 + pp;
    const float* __restrict__ ap = (o < 36) ? (lw + (size_t)o * CIN) : (sw + (size_t)(o - 36) * CIN);
    float acc = 0.f;
    #pragma unroll 1
    for (int g = 0; g < CIN; g += 16) {
      float4 a0 = *(const float4*)(ap + g);
      float4 a1 = *(const float4*)(ap + g + 4);
      float4 a2 = *(const float4*)(ap + g + 8);
      float4 a3 = *(const float4*)(ap + g + 12);
      acc += a0.x * h1c[g +  0][pp];  acc += a0.y * h1c[g +  1][pp];
      acc += a0.z * h1c[g +  2][pp];  acc += a0.w * h1c[g +  3][pp];
      acc += a1.x * h1c[g +  4][pp];  acc += a1.y * h1c[g +  5][pp];
      acc += a1.z * h1c[g +  6][pp];  acc += a1.w * h1c[g +  7][pp];
      acc += a2.x * h1c[g +  8][pp];  acc += a2.y * h1c[g +  9][pp];
      acc += a2.z * h1c[g + 10][pp];  acc += a2.w * h1c[g + 11][pp];
      acc += a3.x * h1c[g + 12][pp];  acc += a3.y * h1c[g + 13][pp];
      acc += a3.z * h1c[g + 14][pp];  acc += a3.w * h1c[g + 15][pp];
    }
    if (p < HW) {
      float bias = (o < 36) ? lb[o] : sb[o - 36];
      c2[(size_t)o * HW + p] = acc + bias;
    }
  }
}

// ------- fused decode + LDS bitonic sort: 16 blocks, 2048 keys each ------------
__global__ __launch_bounds__(256) void decode_sort_kernel(const float* __restrict__ c2, float* __restrict__ roi,
                                                          u64* __restrict__ keys) {
  __shared__ u64 s[2048];
  const int tid = threadIdx.x;
  const int nbase = blockIdx.x * 2048;
  for (int i = tid; i < 2048; i += 256) {
    int n = nbase + i;
    u64 key;
    if (n >= NA) {
      key = ~0ull;
    } else {
      unsigned p = (unsigned)n / 9u;
      unsigned a = (unsigned)n - p * 9u;
      unsigned y = p / 50u;
      unsigned xu = p - y * 50u;
      float dy = c2[(a * 4 + 0) * HW + p];
      float dx = c2[(a * 4 + 1) * HW + p];
      float dh = c2[(a * 4 + 2) * HW + p];
      float dw = c2[(a * 4 + 3) * HW + p];
      float fg = c2[(37 + a * 2) * HW + p];         // score channel a*2+1, rows offset 36
      float sy = (float)(y * 16u), sx = (float)(xu * 16u);
      float ay1 = sy + c_AB[a * 4 + 0], ax1 = sx + c_AB[a * 4 + 1];
      float ay2 = sy + c_AB[a * 4 + 2], ax2 = sx + c_AB[a * 4 + 3];
      float ahh = ay2 - ay1, aww = ax2 - ax1;
      float acy = ay1 + 0.5f * ahh, acx = ax1 + 0.5f * aww;
      float cy = dy * ahh + acy, cx = dx * aww + acx;
      float hh = expf(dh) * ahh, ww = expf(dw) * aww;
      float y1 = cy - 0.5f * hh, x1 = cx - 0.5f * ww;
      float y2 = cy + 0.5f * hh, x2 = cx + 0.5f * ww;
      y1 = fminf(fmaxf(y1, 0.f), 608.f); x1 = fminf(fmaxf(x1, 0.f), 800.f);
      y2 = fminf(fmaxf(y2, 0.f), 608.f); x2 = fminf(fmaxf(x2, 0.f), 800.f);
      *(float4*)&roi[(size_t)n * 4] = make_float4(y1, x1, y2, x2);
      bool valid = ((y2 - y1) >= 16.f) && ((x2 - x1) >= 16.f);
      float sc = valid ? fg : -__builtin_huge_valf();
      unsigned m = __float_as_uint(sc);
      m = (m & 0x80000000u) ? ~m : (m | 0x80000000u);  // monotone map
      unsigned km = ~m;                                 // ascending = descending score
      key = ((u64)km << 32) | (unsigned)n;
    }
    s[i] = key;
  }
  __syncthreads();
  for (int k = 2; k <= 2048; k <<= 1) {
    for (int j = k >> 1; j > 0; j >>= 1) {
      for (int i = tid; i < 2048; i += 256) {
        int l = i ^ j;
        if (l > i) {
          u64 xa = s[i], xb = s[l];
          bool up = ((i & k) == 0);
          if ((xa > xb) == up) { s[i] = xb; s[l] = xa; }
        }
      }
      __syncthreads();
    }
  }
  for (int i = tid; i < 2048; i += 256) keys[nbase + i] = s[i];
}

// ------------------------------ merge-path helper ------------------------------
__device__ inline void merge_path(const u64* __restrict__ A, int nA, const u64* __restrict__ B, int nB,
                                  u64* __restrict__ dst, int d0, int cnt, int outLimit) {
  if (d0 >= outLimit || d0 >= nA + nB) return;
  int lo = d0 > nB ? d0 - nB : 0;
  int hi = d0 < nA ? d0 : nA;
  while (lo < hi) {
    int mid = (lo + hi) >> 1;
    if (A[mid] <= B[d0 - 1 - mid]) lo = mid + 1; else hi = mid;
  }
  int i = lo, j = d0 - lo;
  int end = d0 + cnt;
  if (end > nA + nB) end = nA + nB;
  if (end > outLimit) end = outLimit;
  for (int q = d0; q < end; ++q) {
    u64 v;
    if (i < nA && (j >= nB || A[i] <= B[j])) v = A[i++]; else v = B[j++];
    dst[q] = v;
  }
}

// ------- 4-way merge (2 levels in LDS), truncated to first 6016, 4 blocks ------
__global__ __launch_bounds__(256) void merge4_kernel(const u64* __restrict__ keys, u64* __restrict__ tmp) {
  __shared__ u64 M01[4096];
  __shared__ u64 M23[4096];
  const int tid = threadIdx.x;
  const u64* c = keys + (size_t)blockIdx.x * 8192;
  merge_path(c,        2048, c + 2048, 2048, M01, tid * 16, 16, 4096);
  merge_path(c + 4096, 2048, c + 6144, 2048, M23, tid * 16, 16, 4096);
  __syncthreads();
  merge_path(M01, 4096, M23, 4096, tmp + (size_t)blockIdx.x * TOPN, tid * 24, 24, TOPN);
}

// --- final: 4 lists of 6016 -> top-6016 (LDS) + fused gather (r6-verbatim) -----
__global__ __launch_bounds__(256) void mergefinal_gather_kernel(const u64* __restrict__ tmp,
                                                                const float* __restrict__ roi,
                                                                float* __restrict__ tb, float* __restrict__ areaArr,
                                                                u64* __restrict__ valw) {
  __shared__ u64 L0[TOPN];
  __shared__ u64 L1[TOPN];
  __shared__ u64 F[TOPN];
  const int tid = threadIdx.x;
  merge_path(tmp,            TOPN, tmp + TOPN,     TOPN, L0, tid * 24, 24, TOPN);
  merge_path(tmp + 2 * TOPN, TOPN, tmp + 3 * TOPN, TOPN, L1, tid * 24, 24, TOPN);
  __syncthreads();
  merge_path(L0, TOPN, L1, TOPN, F, tid * 24, 24, TOPN);
  __syncthreads();
  for (int j0 = 0; j0 < TOPN; j0 += 256) {
    int j = j0 + tid;
    u64 key = F[j];
    bool valid = (j < PRE) && ((unsigned)(key >> 32) < 0xFF800000u);   // score > -inf
    if (j < PRE) {
      unsigned idx = (unsigned)key;
      float4 bx = *(const float4*)&roi[(size_t)idx * 4];
      *(float4*)&tb[(size_t)j * 4] = bx;
      areaArr[j] = (bx.z - bx.x) * (bx.w - bx.y);
    }
    u64 mask = __ballot(valid);
    if ((tid & 63) == 0) {
      int wi = j >> 6;
      if (wi < NW) valw[wi] = mask;
    }
  }
}

// --------------- suppression bit-matrix MT[w][i]: bits j in word w -------------
__global__ __launch_bounds__(256) void mask_kernel(const float* __restrict__ tb, const float* __restrict__ areaArr,
                                                   u64* __restrict__ MT) {
  int linear = blockIdx.x * 256 + threadIdx.x;
  if (linear >= NW * PRE) return;
  int w = linear / PRE;
  int i = linear - w * PRE;
  u64 bits = 0;
  int jbase = w * 64;
  if (jbase + 63 > i) {
    float4 bi = *(const float4*)&tb[(size_t)i * 4];
    float ai = areaArr[i];
    int jend = jbase + 64; if (jend > PRE) jend = PRE;
    int jst = jbase > i + 1 ? jbase : i + 1;
    for (int j = jst; j < jend; ++j) {
      float4 bj = *(const float4*)&tb[(size_t)j * 4];
      float ty1 = fmaxf(bi.x, bj.x);
      float tx1 = fmaxf(bi.y, bj.y);
      float ty2 = fminf(bi.z, bj.z);
      float tx2 = fminf(bi.w, bj.w);
      float ih = ty2 - ty1; if (ih < 0.f) ih = 0.f;
      float iw = tx2 - tx1; if (iw < 0.f) iw = 0.f;
      float inter = ih * iw;
      float denom = ai + areaArr[j] - inter;
      if (denom < 1e-9f) denom = 1e-9f;
      if (inter / denom > 0.7f) bits |= (1ull << (j - jbase));
    }
  }
  MT[(size_t)w * MTS + i] = bits;
}

__device__ inline u64 shfl_u64(u64 v, int src) {
  int lo = __shfl((int)(unsigned)(v & 0xffffffffull), src, 64);
  int hi = __shfl((int)(unsigned)(v >> 32), src, 64);
  return ((u64)(unsigned)hi << 32) | (unsigned)lo;
}
__device__ inline u64 shfl_u64_xor(u64 v, int m) {
  int lo = __shfl_xor((int)(unsigned)(v & 0xffffffffull), m, 64);
  int hi = __shfl_xor((int)(unsigned)(v >> 32), m, 64);
  return ((u64)(unsigned)hi << 32) | (unsigned)lo;
}

// --------- single-wave greedy NMS, demand-pull rem (verbatim r6) ---------------
__global__ __launch_bounds__(64) void nms_scan_kernel(const u64* __restrict__ MT, const u64* __restrict__ valw,
                                                      const float* __restrict__ tb, float* __restrict__ out) {
  __shared__ int keepids[POST];
  const int lane = threadIdx.x;
  int kept = 0;
  bool done = false;
  for (int g = 0; g < NW && !done; ++g) {
    const u64* __restrict__ rowg = MT + (size_t)g * MTS;
    u64 rem = 0;
    for (int base = 0; base < kept; base += 64) {
      int kidx = base + lane;
      u64 v = (kidx < kept) ? rowg[keepids[kidx]] : 0ull;
      rem |= v;
    }
    #pragma unroll
    for (int s = 32; s > 0; s >>= 1) rem |= shfl_u64_xor(rem, s);
    int row = g * 64 + lane;
    u64 cur = (row < PRE) ? rowg[row] : 0ull;        // own-word suppression bits
    u64 remaining = valw[g] & ~rem;
    while (remaining) {                               // uniform across lanes
      int c = __builtin_ctzll(remaining);
      if (lane == 0) keepids[kept] = g * 64 + c;
      ++kept;
      if (kept >= POST) { done = true; break; }
      u64 cw = shfl_u64(cur, c);                      // broadcast lane c's word
      u64 above = (c == 63) ? 0ull : (~0ull << (c + 1));
      remaining = remaining & ~cw & above;
    }
  }
  __syncthreads();
  int kmax = kept < POST ? kept : POST;
  for (int rr = lane; rr < kmax; rr += 64) {
    float4 b = *(const float4*)&tb[(size_t)keepids[rr] * 4];
    *(float4*)&out[(size_t)rr * 4] = b;
  }
}

extern "C" void kernel_launch(void* const* d_in, const int* in_sizes, int n_in,
                              void* d_out, int out_size, void* d_ws, size_t ws_size,
                              hipStream_t stream) {
  (void)in_sizes; (void)n_in; (void)ws_size;
  const float* x  = (const float*)d_in[0];
  const float* w1 = (const float*)d_in[1];
  const float* b1 = (const float*)d_in[2];
  const float* lw = (const float*)d_in[3];
  const float* lb = (const float*)d_in[4];
  const float* sw = (const float*)d_in[5];
  const float* sb = (const float*)d_in[6];
  float* out = (float*)d_out;

  char* wp = (char*)d_ws;
  auto alloc = [&](size_t b) -> void* { void* p = wp; wp += (b + 255) & ~(size_t)255; return p; };
  float* xp      = (float*)alloc((size_t)CIN * PH * PW * 4);   // 4.26 MB
  float* wt      = (float*)alloc((size_t)4608 * CIN * 4);      // 9.44 MB
  float* part    = (float*)alloc((size_t)3 * CIN * HW * 4);    // 11.7 MB
  float* c2      = (float*)alloc((size_t)64 * HW * 4);
  float* roi     = (float*)alloc((size_t)NA * 4 * 4);
  u64*   keys    = (u64*)alloc((size_t)NSORT * 8);
  u64*   tmp     = (u64*)alloc((size_t)4 * TOPN * 8);
  float* tb      = (float*)alloc((size_t)PRE * 4 * 4);
  float* areaArr = (float*)alloc((size_t)PRE * 4);
  u64*   valw    = (u64*)alloc((size_t)NW * 8);
  u64*   MT      = (u64*)alloc((size_t)NW * MTS * 8);          // 4.52 MB

  hipMemsetAsync(d_out, 0, (size_t)out_size * 4, stream);

  prep_kernel<<<5184, 256, 0, stream>>>(x, xp, w1, wt);
  conv_gemm_kernel<<<dim3(8, 30, 3), 256, 0, stream>>>(wt, xp, part);
  relu_heads_kernel<<<(HW + PB - 1) / PB, 256, 0, stream>>>(part, b1, lw, sw, lb, sb, c2);
  decode_sort_kernel<<<16, 256, 0, stream>>>(c2, roi, keys);
  merge4_kernel<<<4, 256, 0, stream>>>(keys, tmp);
  mergefinal_gather_kernel<<<1, 256, 0, stream>>>(tmp, roi, tb, areaArr, valw);
  mask_kernel<<<(NW * PRE + 255) / 256, 256, 0, stream>>>(tb, areaArr, MT);
  nms_scan_kernel<<<1, 64, 0, stream>>>(MT, valw, tb, out);
}